// Round 1
// baseline (1986.280 us; speedup 1.0000x reference)
//
#include <hip/hip_runtime.h>
#include <math.h>

#define TPB 256

// softplus for v >= 0: v + log1p(exp(-v))  (stable, exp arg <= 0)
__device__ __forceinline__ float softplus_nn(float v) {
    return v + log1pf(__expf(-v));
}

// One block per batch element b. Handles both signs (s=0: p, s=1: n),
// the dim_reduce (kp^T A kp), 3 GCN layers, and the linear head.
__global__ __launch_bounds__(TPB) void gnn_main(
    const float* __restrict__ A,
    const float* __restrict__ kern_p, const float* __restrict__ kern_n,
    const float* __restrict__ Wp1, const float* __restrict__ Wp2, const float* __restrict__ Wp3,
    const float* __restrict__ Wn1, const float* __restrict__ Wn2, const float* __restrict__ Wn3,
    const float* __restrict__ lin1_w, const float* __restrict__ lin1_b,
    const float* __restrict__ lin2_w, const float* __restrict__ lin2_b,
    float* __restrict__ out)
{
    // LDS: ~29.5 KB -> 5 blocks/CU
    __shared__ float a_ch[200 * 17];   // A chunk, stride 17 (pad) -> conflict-free reads
    __shared__ float kp_lds[200 * 9];  // relu(kernel), stride 9, used in stage 2
    __shared__ float t_lds[200 * 9];   // t = A @ kp
    __shared__ float adj_lds[8 * 9];   // reduced (adjacency for GCN)
    __shared__ float buf1[8 * 9];      // xw scratch
    __shared__ float buf2[8 * 9];      // y_relu scratch
    __shared__ float x_lds[8 * 9];     // gcn layer output
    __shared__ float p3_lds[8 * 9];    // saved p3
    __shared__ float h_lds[16];

    const int tid = threadIdx.x;
    const int b = blockIdx.x;
    const int ii = tid >> 3;   // row (tid<64)
    const int jj = tid & 7;    // col (tid<64)

    for (int s = 0; s < 2; ++s) {
        const float* kern = s ? kern_n : kern_p;
        const float* W1 = s ? Wn1 : Wp1;
        const float* W2 = s ? Wn2 : Wp2;
        const float* W3 = s ? Wn3 : Wp3;
        const float* Ab = A + (size_t)(b * 2 + s) * 40000;

        __syncthreads();  // protect kp_lds/t_lds reuse across s
        // stage relu(kernel) into LDS (for stage 2)
        for (int i = tid; i < 1600; i += TPB)
            kp_lds[(i >> 3) * 9 + (i & 7)] = fmaxf(kern[i], 0.f);

        float acc[8];
#pragma unroll
        for (int k = 0; k < 8; ++k) acc[k] = 0.f;

        // ---- stage 1: t[n][k] = sum_m A[n][m] * relu(kern[m][k]) ----
        // 12 main chunks of 16 cols
        for (int m0 = 0; m0 < 192; m0 += 16) {
            __syncthreads();
            for (int i = tid; i < 800; i += TPB) {      // 200 rows x 4 float4
                int r = i >> 2, c4 = i & 3;
                float4 v = *(const float4*)(Ab + r * 200 + m0 + (c4 << 2));
                float* d = &a_ch[r * 17 + (c4 << 2)];
                d[0] = v.x; d[1] = v.y; d[2] = v.z; d[3] = v.w;
            }
            __syncthreads();
            if (tid < 200) {
                const float* ar = &a_ch[tid * 17];
#pragma unroll
                for (int j = 0; j < 16; ++j) {
                    float a = ar[j];
                    const float* km = kern + ((m0 + j) << 3);  // wave-uniform addr
#pragma unroll
                    for (int k = 0; k < 8; ++k)
                        acc[k] = fmaf(a, fmaxf(km[k], 0.f), acc[k]);
                }
            }
        }
        // tail chunk: cols 192..199
        __syncthreads();
        for (int i = tid; i < 400; i += TPB) {          // 200 rows x 2 float4
            int r = i >> 1, c4 = i & 1;
            float4 v = *(const float4*)(Ab + r * 200 + 192 + (c4 << 2));
            float* d = &a_ch[r * 17 + (c4 << 2)];
            d[0] = v.x; d[1] = v.y; d[2] = v.z; d[3] = v.w;
        }
        __syncthreads();
        if (tid < 200) {
            const float* ar = &a_ch[tid * 17];
#pragma unroll
            for (int j = 0; j < 8; ++j) {
                float a = ar[j];
                const float* km = kern + ((192 + j) << 3);
#pragma unroll
                for (int k = 0; k < 8; ++k)
                    acc[k] = fmaf(a, fmaxf(km[k], 0.f), acc[k]);
            }
#pragma unroll
            for (int k = 0; k < 8; ++k) t_lds[tid * 9 + k] = acc[k];
        }
        __syncthreads();

        // ---- stage 2: reduced[a][k] = sum_n kp[n][a] * t[n][k] ----
        if (tid < 64) {
            float r = 0.f;
            for (int n = 0; n < 200; ++n)
                r = fmaf(kp_lds[n * 9 + ii], t_lds[n * 9 + jj], r);
            adj_lds[ii * 9 + jj] = r;
        }
        __syncthreads();

        // ---- 3 GCN layers on the 8x8 adjacency ----
        float xv = 0.f;
        for (int layer = 0; layer < 3; ++layer) {
            const float* W = (layer == 0) ? W1 : ((layer == 1) ? W2 : W3);
            float axw = 0.f;
            if (layer == 0) {
                if (tid < 64) {
#pragma unroll
                    for (int k = 0; k < 8; ++k)
                        axw = fmaf(adj_lds[ii * 9 + k], W[(k << 3) + jj], axw);
                }
            } else {
                if (tid < 64) {
                    float xw = 0.f;
#pragma unroll
                    for (int k = 0; k < 8; ++k)
                        xw = fmaf(x_lds[ii * 9 + k], W[(k << 3) + jj], xw);
                    buf1[ii * 9 + jj] = xw;
                }
                __syncthreads();
                if (tid < 64) {
#pragma unroll
                    for (int k = 0; k < 8; ++k)
                        axw = fmaf(adj_lds[ii * 9 + k], buf1[k * 9 + jj], axw);
                }
            }
            if (tid < 64) {
                float y = fmaxf((ii == jj ? 1.f : 0.f) + 0.85f * axw, 0.f);
                buf2[ii * 9 + jj] = y;
            }
            __syncthreads();
            if (tid < 64) {
                float cs = 0.f;
#pragma unroll
                for (int i8 = 0; i8 < 8; ++i8) cs += buf2[i8 * 9 + jj];
                float cm = cs * 0.125f + 1e-6f;
                float v = buf2[ii * 9 + jj] / cm;
                xv = softplus_nn(v);
            }
            __syncthreads();   // x_lds readers of previous layer are done
            if (tid < 64) x_lds[ii * 9 + jj] = xv;
            __syncthreads();
        }
        if (s == 0 && tid < 64) p3_lds[ii * 9 + jj] = xv;  // save p3; n3 stays in x_lds
        __syncthreads();
    }

    // ---- linear head: cc[128] = concat(p3, n3, axis=-1).flatten() ----
    if (tid < 16) {
        float h = lin1_b[tid];
        const float* w = lin1_w + tid * 128;
        for (int q = 0; q < 128; ++q) {
            int i = q >> 4, t = q & 15;
            float c = (t < 8) ? p3_lds[i * 9 + t] : x_lds[i * 9 + (t - 8)];
            h = fmaf(c, w[q], h);
        }
        h_lds[tid] = h;
    }
    __syncthreads();
    if (tid < 2) {
        float o = lin2_b[tid];
#pragma unroll
        for (int k = 0; k < 16; ++k)
            o = fmaf(h_lds[k], lin2_w[(tid << 4) + k], o);
        out[b * 2 + tid] = o;
    }
}

// All loss terms are independent of A: single tiny block.
__global__ __launch_bounds__(TPB) void gnn_loss(
    const float* __restrict__ kp_, const float* __restrict__ kn_,
    const float* __restrict__ Wp1, const float* __restrict__ Wp2, const float* __restrict__ Wp3,
    const float* __restrict__ Wn1, const float* __restrict__ Wn2, const float* __restrict__ Wn3,
    float* __restrict__ out)
{
    __shared__ float red[TPB];
    __shared__ float diag[16];  // [0:8]=p, [8:16]=n
    const int tid = threadIdx.x;
    float part = 0.f;

    // neg-penalty (0.1) on raw kernel + L1 (0.05) on relu(kernel), both signs
    for (int i = tid; i < 1600; i += TPB) {
        float v = kp_[i];
        part += 0.1f * fmaxf(1e-6f - v, 0.f) + 0.05f * fmaxf(v, 0.f);
        float w = kn_[i];
        part += 0.1f * fmaxf(1e-6f - w, 0.f) + 0.05f * fmaxf(w, 0.f);
    }
    if (tid < 64) {
        // GCN W neg losses (0.2 each, 6 matrices)
        part += 0.2f * (fmaxf(1e-6f - Wp1[tid], 0.f) + fmaxf(1e-6f - Wp2[tid], 0.f) +
                        fmaxf(1e-6f - Wp3[tid], 0.f) + fmaxf(1e-6f - Wn1[tid], 0.f) +
                        fmaxf(1e-6f - Wn2[tid], 0.f) + fmaxf(1e-6f - Wn3[tid], 0.f));
        // gram = kp^T kp ; ortho penalty on off-diagonal squares
        int a = tid >> 3, c = tid & 7;
        float gp = 0.f, gn = 0.f;
        for (int n = 0; n < 200; ++n) {
            gp = fmaf(fmaxf(kp_[n * 8 + a], 0.f), fmaxf(kp_[n * 8 + c], 0.f), gp);
            gn = fmaf(fmaxf(kn_[n * 8 + a], 0.f), fmaxf(kn_[n * 8 + c], 0.f), gn);
        }
        if (a != c) part += 0.2f * (gp * gp + gn * gn);
        else { diag[a] = gp; diag[8 + a] = gn; }
    }
    red[tid] = part;
    __syncthreads();
    for (int s2 = 128; s2 > 0; s2 >>= 1) {
        if (tid < s2) red[tid] += red[tid + s2];
        __syncthreads();
    }
    if (tid == 0) {
        float mp = 0.f, mn = 0.f;
        for (int i = 0; i < 8; ++i) { mp += diag[i]; mn += diag[8 + i]; }
        mp *= 0.125f; mn *= 0.125f;
        float vp = 0.f, vn = 0.f;
        for (int i = 0; i < 8; ++i) {
            float dp = diag[i] - mp; vp = fmaf(dp, dp, vp);
            float dn = diag[8 + i] - mn; vn = fmaf(dn, dn, vn);
        }
        // var with ddof=1 -> /7 ; penalties 0.3 (p) and 0.5 (n)
        out[8192] = red[0] + 0.3f * (vp / 7.f) + 0.5f * (vn / 7.f);
    }
}

extern "C" void kernel_launch(void* const* d_in, const int* in_sizes, int n_in,
                              void* d_out, int out_size, void* d_ws, size_t ws_size,
                              hipStream_t stream) {
    const float* A      = (const float*)d_in[0];
    const float* kp     = (const float*)d_in[1];
    const float* kn     = (const float*)d_in[2];
    const float* Wp1    = (const float*)d_in[3];
    const float* Wp2    = (const float*)d_in[4];
    const float* Wp3    = (const float*)d_in[5];
    const float* Wn1    = (const float*)d_in[6];
    const float* Wn2    = (const float*)d_in[7];
    const float* Wn3    = (const float*)d_in[8];
    const float* lin1_w = (const float*)d_in[9];
    const float* lin1_b = (const float*)d_in[10];
    const float* lin2_w = (const float*)d_in[11];
    const float* lin2_b = (const float*)d_in[12];
    float* out = (float*)d_out;

    gnn_main<<<4096, TPB, 0, stream>>>(A, kp, kn, Wp1, Wp2, Wp3, Wn1, Wn2, Wn3,
                                       lin1_w, lin1_b, lin2_w, lin2_b, out);
    gnn_loss<<<1, TPB, 0, stream>>>(kp, kn, Wp1, Wp2, Wp3, Wn1, Wn2, Wn3, out);
}